// Round 12
// baseline (461.841 us; speedup 1.0000x reference)
//
#include <hip/hip_runtime.h>
#include <math.h>

#define EPSV 1e-5
#define HW_IN (240 * 320)
#define NPTS 300
#define NPATCH 4800
#define KC 64        // one input channel per chunk
#define EPS_BLEND 2.5e-4
#define W_MAX 0.35

// ---------------- weight transpose to f64: wT[k][oc] = (double)w[oc][k] ----------------
__global__ __launch_bounds__(256) void k_wt(const float* __restrict__ w, double* __restrict__ wT) {
    int t = blockIdx.x * 256 + threadIdx.x;   // t = k*16 + oc
    int k = t >> 4, oc = t & 15;
    wT[t] = (double)w[oc * 16384 + k];
}

// ---------------- conv chunk (f64 accumulate, f32 partial out): part[ic][p][oc] ----------------
// grid (75, 64), block 256 = 4 waves. Wave w computes oc-group w (4 accs) for the block's
// 64 patches -> 19200 waves (8/SIMD occupancy), 4x shorter per-wave chains. Weight reads
// stay wave-uniform (scalar path). Per-(p,oc) FMA k-order unchanged -> feat BIT-IDENTICAL.
__global__ __launch_bounds__(256) void k_conv(const float* __restrict__ x, const double* __restrict__ wT,
                                              float* __restrict__ part) {
    int tid = threadIdx.x;
    int lane = tid & 63;                      // patch within block
    int ocg = tid >> 6;                       // oc group 0..3 (wave-uniform)
    int p = blockIdx.x * 64 + lane;           // 0..4799
    int ic = blockIdx.y;                      // 0..63
    int b = p / NPTS;
    int r = p - b * NPTS;
    int oh = r / 20;
    int ow = r - oh * 20;
    const float* xp = x + (size_t)b * (64 * HW_IN) + (size_t)ic * HW_IN + (oh * 16) * 320 + ow * 16;
    const double* wk = wT + (size_t)(ic * 256) * 16 + ocg * 4;   // wave-uniform base
    double acc[4];
#pragma unroll
    for (int o = 0; o < 4; ++o) acc[o] = 0.0;

    float4 cur0, cur1, cur2, cur3, nxt0, nxt1, nxt2, nxt3;
    {
        const float4* rp = (const float4*)xp;
        cur0 = rp[0]; cur1 = rp[1]; cur2 = rp[2]; cur3 = rp[3];
    }
    for (int kh = 0; kh < 16; ++kh) {
        if (kh < 15) {                        // prefetch next row before the FMA block
            const float4* rn = (const float4*)(xp + (kh + 1) * 320);
            nxt0 = rn[0]; nxt1 = rn[1]; nxt2 = rn[2]; nxt3 = rn[3];
        }
        float4 rq[4] = {cur0, cur1, cur2, cur3};
#pragma unroll
        for (int q = 0; q < 4; ++q) {
            float xe[4] = {rq[q].x, rq[q].y, rq[q].z, rq[q].w};
#pragma unroll
            for (int e = 0; e < 4; ++e) {
                double xd = (double)xe[e];
                const double* wq = wk + (size_t)(kh * 16 + q * 4 + e) * 16;  // wave-uniform
#pragma unroll
                for (int o = 0; o < 4; ++o) acc[o] += xd * wq[o];
            }
        }
        cur0 = nxt0; cur1 = nxt1; cur2 = nxt2; cur3 = nxt3;
    }
    float4* dst = (float4*)(part + ((size_t)ic * NPATCH + p) * 16 + ocg * 4);
    dst[0] = make_float4((float)acc[0], (float)acc[1], (float)acc[2], (float)acc[3]);
}

// ---------------- reduce partials (ic order) + bias + BN1 + relu -> feat f64 (B,N,C) ----------------
__global__ __launch_bounds__(256) void k_reduce(const float* __restrict__ part, const float* __restrict__ cb,
                                                const float* __restrict__ g, const float* __restrict__ be,
                                                const float* __restrict__ mu, const float* __restrict__ va,
                                                double* __restrict__ feat) {
    int t = blockIdx.x * 256 + threadIdx.x;   // (p, oc) flat, 76800 total
    double s = 0.0;
#pragma unroll 8
    for (int ic = 0; ic < KC; ++ic) s += (double)part[(size_t)ic * 76800 + t];
    int oc = t & 15;
    double v = s + (double)cb[oc];
    double rs = 1.0 / sqrt((double)va[oc] + EPSV);
    double f = (double)g[oc] * (v - (double)mu[oc]) * rs + (double)be[oc];
    feat[t] = fmax(f, 0.0);
}

// ---------------- attention gate: grid 16 (one per batch) ----------------
__global__ __launch_bounds__(256) void k_atten(const double* __restrict__ feat, const float* __restrict__ aw,
                                               const float* __restrict__ g2, const float* __restrict__ be2,
                                               const float* __restrict__ mu2, const float* __restrict__ va2,
                                               double* __restrict__ sg) {
    __shared__ double partial[256];
    __shared__ double am[16];
    int b = blockIdx.x;
    int t = threadIdx.x;
    int c = t & 15, seg = t >> 4;
    double s = 0.0;
    for (int n = seg; n < NPTS; n += 16) s += feat[(size_t)b * 4800 + n * 16 + c];
    partial[t] = s;
    __syncthreads();
    if (t < 16) {
        double s2 = 0.0;
        for (int sgm = 0; sgm < 16; ++sgm) s2 += partial[sgm * 16 + t];
        am[t] = s2 / 300.0;
    }
    __syncthreads();
    if (t < 16) {
        double a = 0.0;
        for (int j = 0; j < 16; ++j) a += am[j] * (double)aw[t * 16 + j];
        double rs = 1.0 / sqrt((double)va2[t] + EPSV);
        double v = (double)g2[t] * (a - (double)mu2[t]) * rs + (double)be2[t];
        sg[b * 16 + t] = 1.0 / (1.0 + exp(-v));
    }
}

// ---------------- per-(b,i): f64 dist -> rank count (b128 key reads) -> hedged mean -> linear ----------------
__global__ __launch_bounds__(320) void k_knn(const double* __restrict__ feat, const double* __restrict__ sg,
                                             const float* __restrict__ lw, const float* __restrict__ lb,
                                             double* __restrict__ ke) {
    __shared__ __align__(16) double dsh[NPTS];
    __shared__ short rankidx[NPTS];
    __shared__ double qv[16];
    __shared__ double sgs[16];
    __shared__ double mvec[16];
    const int tid = threadIdx.x;
    const int blk = blockIdx.x;
    const int b = blk / NPTS;
    const int i = blk - b * NPTS;
    const double* fb = feat + (size_t)b * 4800;

    if (tid < NPTS) rankidx[tid] = (short)tid;   // guard for measure-zero exact ties
    if (tid < 16) {
        double sv = sg[b * 16 + tid];
        sgs[tid] = sv;
        qv[tid] = fb[i * 16 + tid] * sv;
    }
    __syncthreads();
    if (tid < NPTS) {
        const double* fr = fb + (size_t)tid * 16;
        double s2 = 0.0;
#pragma unroll
        for (int c = 0; c < 16; ++c) {
            double d = qv[c] - fr[c] * sgs[c];
            s2 += d * d;
        }
        dsh[tid] = sqrt(s2);
    }
    __syncthreads();
    if (tid < NPTS) {
        double dj = dsh[tid];
        int rank = 0;
        const double2* d2 = (const double2*)dsh;
#pragma unroll 10
        for (int t = 0; t < 150; ++t) {
            double2 kk = d2[t];                  // broadcast ds_read_b128: 2 keys/op
            rank += (kk.x > dj);
            rank += (kk.y > dj);                 // exact ties measure-zero in f64
        }
        rankidx[rank] = (short)tid;
    }
    __syncthreads();
    if (tid < 16) {   // tid = channel c; hedged mean over the 16 selected ranks
        const int targ[16] = {9, 28, 46, 65, 84, 103, 121, 140, 159, 178,
                              196, 215, 234, 253, 271, 290};
        double acc = 0.0;
        double sc = sgs[tid];
        for (int s = 0; s < 16; ++s) {
            int r = targ[s];
            int a  = rankidx[r];
            int u  = rankidx[r - 1];
            int dn = rankidx[r + 1];
            double gu = dsh[u] - dsh[a];
            double gd = dsh[a] - dsh[dn];
            double wu = W_MAX * fmax(0.0, 1.0 - gu / EPS_BLEND);
            double wd = W_MAX * fmax(0.0, 1.0 - gd / EPS_BLEND);
            double wa = 1.0 - wu - wd;
            acc += wa * (fb[a * 16 + tid] * sc) + wu * (fb[u * 16 + tid] * sc)
                 + wd * (fb[dn * 16 + tid] * sc);
        }
        mvec[tid] = acc * (1.0 / 16.0) - qv[tid];
    }
    __syncthreads();
    if (tid < 16) {   // tid = out channel
        double o = (double)lb[tid];
        for (int c = 0; c < 16; ++c) o += mvec[c] * (double)lw[tid * 16 + c];
        ke[((size_t)b * 16 + tid) * NPTS + i] = o;
    }
}

// ---------------- fused double-bilinear 2x->4x + positional encoding ----------------
__device__ inline void coords2x(int o, int n, int& i0, int& i1, double& w) {
    double s = ((double)o + 0.5) * 0.5 - 0.5;
    s = fmin(fmax(s, 0.0), (double)(n - 1));
    i0 = (int)floor(s);
    i1 = min(i0 + 1, n - 1);
    w = s - (double)i0;
}

__device__ inline double midval(const double* __restrict__ kp, int y, int x) {
    int y0, y1, x0, x1; double wy, wx;
    coords2x(y, 15, y0, y1, wy);
    coords2x(x, 20, x0, x1, wx);
    double v00 = kp[y0 * 20 + x0], v01 = kp[y0 * 20 + x1];
    double v10 = kp[y1 * 20 + x0], v11 = kp[y1 * 20 + x1];
    return (v00 * (1.0 - wy) + v10 * wy) * (1.0 - wx) + (v01 * (1.0 - wy) + v11 * wy) * wx;
}

__global__ __launch_bounds__(256) void k_up(const double* __restrict__ ke, float* __restrict__ out) {
    int idx = blockIdx.x * 256 + threadIdx.x;   // (b, c, 60, 80) = 1,228,800 threads
    int bc = idx / 4800;
    int r2 = idx - bc * 4800;
    int Y = r2 / 80, X = r2 - Y * 80;
    int c = bc & 15;
    int y0, y1, x0, x1; double wy, wx;
    coords2x(Y, 30, y0, y1, wy);
    coords2x(X, 40, x0, x1, wx);
    const double* kp = ke + (size_t)bc * 300;
    double v00 = midval(kp, y0, x0), v01 = midval(kp, y0, x1);
    double v10 = midval(kp, y1, x0), v11 = midval(kp, y1, x1);
    double u = (v00 * (1.0 - wy) + v10 * wy) * (1.0 - wx) + (v01 * (1.0 - wy) + v11 * wy) * wx;
    const float scf[4] = {1.0f, 0.1f, 0.01f, 0.001f};   // exp(-2m*ln(1e4)/8) = 10^-m
    int m = c >> 2, rr = c & 3;
    float pos = (rr < 2) ? (float)(X + 1) : (float)(Y + 1);
    float ang = pos * scf[m];
    float pe = (rr & 1) ? cosf(ang) : sinf(ang);    // f32 trig: smooth path, error ~1e-7
    out[idx] = (float)(u + (u + (double)pe));       // knn_edge + (knn_edge + pe)
}

extern "C" void kernel_launch(void* const* d_in, const int* in_sizes, int n_in,
                              void* d_out, int out_size, void* d_ws, size_t ws_size,
                              hipStream_t stream) {
    const float* x      = (const float*)d_in[0];
    const float* conv_w = (const float*)d_in[1];
    const float* conv_b = (const float*)d_in[2];
    const float* g1     = (const float*)d_in[3];
    const float* b1     = (const float*)d_in[4];
    const float* m1     = (const float*)d_in[5];
    const float* v1     = (const float*)d_in[6];
    const float* aw     = (const float*)d_in[7];
    const float* g2     = (const float*)d_in[8];
    const float* b2     = (const float*)d_in[9];
    const float* m2     = (const float*)d_in[10];
    const float* v2     = (const float*)d_in[11];
    const float* lw     = (const float*)d_in[12];
    const float* lb     = (const float*)d_in[13];
    float* out = (float*)d_out;

    double* ws   = (double*)d_ws;
    double* wT   = ws;                     // 262144 d (2.10 MB)
    double* feat = wT + 262144;            // 76800 d
    double* sg   = feat + 76800;           // 256 d
    double* ke   = sg + 256;               // 76800 d
    float*  part = (float*)(ke + 76800);   // 64*76800 f32 = 19.66 MB

    k_wt<<<1024, 256, 0, stream>>>(conv_w, wT);
    k_conv<<<dim3(75, KC), 256, 0, stream>>>(x, wT, part);
    k_reduce<<<300, 256, 0, stream>>>(part, conv_b, g1, b1, m1, v1, feat);
    k_atten<<<16, 256, 0, stream>>>(feat, aw, g2, b2, m2, v2, sg);
    k_knn<<<4800, 320, 0, stream>>>(feat, sg, lw, lb, ke);
    k_up<<<4800, 256, 0, stream>>>(ke, out);
}

// Round 13
// 407.201 us; speedup vs baseline: 1.1342x; 1.1342x over previous
//
#include <hip/hip_runtime.h>
#include <math.h>

#define EPSV 1e-5
#define HW_IN (240 * 320)
#define NPTS 300
#define NPATCH 4800
#define KC 64        // one input channel per chunk
#define EPS_BLEND 2.5e-4
#define W_MAX 0.35

// ---------------- weight transpose to f64: wT[k][oc] = (double)w[oc][k] ----------------
__global__ __launch_bounds__(256) void k_wt(const float* __restrict__ w, double* __restrict__ wT) {
    int t = blockIdx.x * 256 + threadIdx.x;   // t = k*16 + oc
    int k = t >> 4, oc = t & 15;
    wT[t] = (double)w[oc * 16384 + k];
}

// ---------------- conv chunk: part[ic][p][oc], f64 accumulate, f32 out ----------------
// grid (75, 64), block 256 = 4 waves. Wave w handles kh rows [4w, 4w+4) of the SAME 64
// patches: x traffic has zero redundancy, per-wave s_load stream drops 4x, and 19200
// waves overlap the scalar-load stalls that bound r11 (r12 evidence). Quarter sums
// combine in LDS in kh order (f64 regroup, ~1e-16 rel on feat — hedge-protected).
__global__ __launch_bounds__(256) void k_conv(const float* __restrict__ x, const double* __restrict__ wT,
                                              float* __restrict__ part) {
    __shared__ double lacc[3][16][64];        // waves 1..3 partials; [o][lane] -> 2-way bank alias only
    int tid = threadIdx.x;
    int lane = tid & 63;                      // patch within block
    int wv = tid >> 6;                        // kh quarter 0..3 (wave-uniform)
    int p = blockIdx.x * 64 + lane;           // 0..4799
    int ic = blockIdx.y;                      // 0..63
    int b = p / NPTS;
    int r = p - b * NPTS;
    int oh = r / 20;
    int ow = r - oh * 20;
    const float* xp = x + (size_t)b * (64 * HW_IN) + (size_t)ic * HW_IN
                        + (size_t)(oh * 16 + wv * 4) * 320 + ow * 16;
    const double* wk = wT + (size_t)(ic * 256 + wv * 64) * 16;
    double acc[16];
#pragma unroll
    for (int o = 0; o < 16; ++o) acc[o] = 0.0;

    float4 cur0, cur1, cur2, cur3, nxt0, nxt1, nxt2, nxt3;
    {
        const float4* rp = (const float4*)xp;
        cur0 = rp[0]; cur1 = rp[1]; cur2 = rp[2]; cur3 = rp[3];
    }
    for (int kh = 0; kh < 4; ++kh) {
        if (kh < 3) {                         // prefetch next row before the FMA block
            const float4* rn = (const float4*)(xp + (kh + 1) * 320);
            nxt0 = rn[0]; nxt1 = rn[1]; nxt2 = rn[2]; nxt3 = rn[3];
        }
        float4 rq[4] = {cur0, cur1, cur2, cur3};
#pragma unroll
        for (int q = 0; q < 4; ++q) {
            float xe[4] = {rq[q].x, rq[q].y, rq[q].z, rq[q].w};
#pragma unroll
            for (int e = 0; e < 4; ++e) {
                double xd = (double)xe[e];
                const double* wq = wk + (size_t)(kh * 16 + q * 4 + e) * 16;  // wave-uniform
#pragma unroll
                for (int o = 0; o < 16; ++o) acc[o] += xd * wq[o];
            }
        }
        cur0 = nxt0; cur1 = nxt1; cur2 = nxt2; cur3 = nxt3;
    }
    if (wv > 0) {
#pragma unroll
        for (int o = 0; o < 16; ++o) lacc[wv - 1][o][lane] = acc[o];
    }
    __syncthreads();
    if (wv == 0) {
        double s[16];
#pragma unroll
        for (int o = 0; o < 16; ++o) {        // fixed kh order: q0 + q1 + q2 + q3
            double v = acc[o] + lacc[0][o][lane];
            v += lacc[1][o][lane];
            v += lacc[2][o][lane];
            s[o] = v;
        }
        float4* dst = (float4*)(part + ((size_t)ic * NPATCH + p) * 16);
#pragma unroll
        for (int q = 0; q < 4; ++q)
            dst[q] = make_float4((float)s[4 * q], (float)s[4 * q + 1],
                                 (float)s[4 * q + 2], (float)s[4 * q + 3]);
    }
}

// ---------------- reduce partials (ic order) + bias + BN1 + relu -> feat f64 (B,N,C) ----------------
__global__ __launch_bounds__(256) void k_reduce(const float* __restrict__ part, const float* __restrict__ cb,
                                                const float* __restrict__ g, const float* __restrict__ be,
                                                const float* __restrict__ mu, const float* __restrict__ va,
                                                double* __restrict__ feat) {
    int t = blockIdx.x * 256 + threadIdx.x;   // (p, oc) flat, 76800 total
    double s = 0.0;
#pragma unroll 8
    for (int ic = 0; ic < KC; ++ic) s += (double)part[(size_t)ic * 76800 + t];
    int oc = t & 15;
    double v = s + (double)cb[oc];
    double rs = 1.0 / sqrt((double)va[oc] + EPSV);
    double f = (double)g[oc] * (v - (double)mu[oc]) * rs + (double)be[oc];
    feat[t] = fmax(f, 0.0);
}

// ---------------- attention gate: grid 16 (one per batch) ----------------
__global__ __launch_bounds__(256) void k_atten(const double* __restrict__ feat, const float* __restrict__ aw,
                                               const float* __restrict__ g2, const float* __restrict__ be2,
                                               const float* __restrict__ mu2, const float* __restrict__ va2,
                                               double* __restrict__ sg) {
    __shared__ double partial[256];
    __shared__ double am[16];
    int b = blockIdx.x;
    int t = threadIdx.x;
    int c = t & 15, seg = t >> 4;
    double s = 0.0;
    for (int n = seg; n < NPTS; n += 16) s += feat[(size_t)b * 4800 + n * 16 + c];
    partial[t] = s;
    __syncthreads();
    if (t < 16) {
        double s2 = 0.0;
        for (int sgm = 0; sgm < 16; ++sgm) s2 += partial[sgm * 16 + t];
        am[t] = s2 / 300.0;
    }
    __syncthreads();
    if (t < 16) {
        double a = 0.0;
        for (int j = 0; j < 16; ++j) a += am[j] * (double)aw[t * 16 + j];
        double rs = 1.0 / sqrt((double)va2[t] + EPSV);
        double v = (double)g2[t] * (a - (double)mu2[t]) * rs + (double)be2[t];
        sg[b * 16 + t] = 1.0 / (1.0 + exp(-v));
    }
}

// ---------------- per-(b,i): f64 dist -> rank count (b128 key reads) -> hedged mean -> linear ----------------
__global__ __launch_bounds__(320) void k_knn(const double* __restrict__ feat, const double* __restrict__ sg,
                                             const float* __restrict__ lw, const float* __restrict__ lb,
                                             double* __restrict__ ke) {
    __shared__ __align__(16) double dsh[NPTS];
    __shared__ short rankidx[NPTS];
    __shared__ double qv[16];
    __shared__ double sgs[16];
    __shared__ double mvec[16];
    const int tid = threadIdx.x;
    const int blk = blockIdx.x;
    const int b = blk / NPTS;
    const int i = blk - b * NPTS;
    const double* fb = feat + (size_t)b * 4800;

    if (tid < NPTS) rankidx[tid] = (short)tid;   // guard for measure-zero exact ties
    if (tid < 16) {
        double sv = sg[b * 16 + tid];
        sgs[tid] = sv;
        qv[tid] = fb[i * 16 + tid] * sv;
    }
    __syncthreads();
    if (tid < NPTS) {
        const double* fr = fb + (size_t)tid * 16;
        double s2 = 0.0;
#pragma unroll
        for (int c = 0; c < 16; ++c) {
            double d = qv[c] - fr[c] * sgs[c];
            s2 += d * d;
        }
        dsh[tid] = sqrt(s2);
    }
    __syncthreads();
    if (tid < NPTS) {
        double dj = dsh[tid];
        int rank = 0;
        const double2* d2 = (const double2*)dsh;
#pragma unroll 10
        for (int t = 0; t < 150; ++t) {
            double2 kk = d2[t];                  // broadcast ds_read_b128: 2 keys/op
            rank += (kk.x > dj);
            rank += (kk.y > dj);                 // exact ties measure-zero in f64
        }
        rankidx[rank] = (short)tid;
    }
    __syncthreads();
    if (tid < 16) {   // tid = channel c; hedged mean over the 16 selected ranks
        const int targ[16] = {9, 28, 46, 65, 84, 103, 121, 140, 159, 178,
                              196, 215, 234, 253, 271, 290};
        double acc = 0.0;
        double sc = sgs[tid];
        for (int s = 0; s < 16; ++s) {
            int r = targ[s];
            int a  = rankidx[r];
            int u  = rankidx[r - 1];
            int dn = rankidx[r + 1];
            double gu = dsh[u] - dsh[a];
            double gd = dsh[a] - dsh[dn];
            double wu = W_MAX * fmax(0.0, 1.0 - gu / EPS_BLEND);
            double wd = W_MAX * fmax(0.0, 1.0 - gd / EPS_BLEND);
            double wa = 1.0 - wu - wd;
            acc += wa * (fb[a * 16 + tid] * sc) + wu * (fb[u * 16 + tid] * sc)
                 + wd * (fb[dn * 16 + tid] * sc);
        }
        mvec[tid] = acc * (1.0 / 16.0) - qv[tid];
    }
    __syncthreads();
    if (tid < 16) {   // tid = out channel
        double o = (double)lb[tid];
        for (int c = 0; c < 16; ++c) o += mvec[c] * (double)lw[tid * 16 + c];
        ke[((size_t)b * 16 + tid) * NPTS + i] = o;
    }
}

// ---------------- fused double-bilinear 2x->4x + positional encoding ----------------
__device__ inline void coords2x(int o, int n, int& i0, int& i1, double& w) {
    double s = ((double)o + 0.5) * 0.5 - 0.5;
    s = fmin(fmax(s, 0.0), (double)(n - 1));
    i0 = (int)floor(s);
    i1 = min(i0 + 1, n - 1);
    w = s - (double)i0;
}

__device__ inline double midval(const double* __restrict__ kp, int y, int x) {
    int y0, y1, x0, x1; double wy, wx;
    coords2x(y, 15, y0, y1, wy);
    coords2x(x, 20, x0, x1, wx);
    double v00 = kp[y0 * 20 + x0], v01 = kp[y0 * 20 + x1];
    double v10 = kp[y1 * 20 + x0], v11 = kp[y1 * 20 + x1];
    return (v00 * (1.0 - wy) + v10 * wy) * (1.0 - wx) + (v01 * (1.0 - wy) + v11 * wy) * wx;
}

__global__ __launch_bounds__(256) void k_up(const double* __restrict__ ke, float* __restrict__ out) {
    int idx = blockIdx.x * 256 + threadIdx.x;   // (b, c, 60, 80) = 1,228,800 threads
    int bc = idx / 4800;
    int r2 = idx - bc * 4800;
    int Y = r2 / 80, X = r2 - Y * 80;
    int c = bc & 15;
    int y0, y1, x0, x1; double wy, wx;
    coords2x(Y, 30, y0, y1, wy);
    coords2x(X, 40, x0, x1, wx);
    const double* kp = ke + (size_t)bc * 300;
    double v00 = midval(kp, y0, x0), v01 = midval(kp, y0, x1);
    double v10 = midval(kp, y1, x0), v11 = midval(kp, y1, x1);
    double u = (v00 * (1.0 - wy) + v10 * wy) * (1.0 - wx) + (v01 * (1.0 - wy) + v11 * wy) * wx;
    const float scf[4] = {1.0f, 0.1f, 0.01f, 0.001f};   // exp(-2m*ln(1e4)/8) = 10^-m
    int m = c >> 2, rr = c & 3;
    float pos = (rr < 2) ? (float)(X + 1) : (float)(Y + 1);
    float ang = pos * scf[m];
    float pe = (rr & 1) ? cosf(ang) : sinf(ang);    // f32 trig: smooth path, error ~1e-7
    out[idx] = (float)(u + (u + (double)pe));       // knn_edge + (knn_edge + pe)
}

extern "C" void kernel_launch(void* const* d_in, const int* in_sizes, int n_in,
                              void* d_out, int out_size, void* d_ws, size_t ws_size,
                              hipStream_t stream) {
    const float* x      = (const float*)d_in[0];
    const float* conv_w = (const float*)d_in[1];
    const float* conv_b = (const float*)d_in[2];
    const float* g1     = (const float*)d_in[3];
    const float* b1     = (const float*)d_in[4];
    const float* m1     = (const float*)d_in[5];
    const float* v1     = (const float*)d_in[6];
    const float* aw     = (const float*)d_in[7];
    const float* g2     = (const float*)d_in[8];
    const float* b2     = (const float*)d_in[9];
    const float* m2     = (const float*)d_in[10];
    const float* v2     = (const float*)d_in[11];
    const float* lw     = (const float*)d_in[12];
    const float* lb     = (const float*)d_in[13];
    float* out = (float*)d_out;

    double* ws   = (double*)d_ws;
    double* wT   = ws;                     // 262144 d (2.10 MB)
    double* feat = wT + 262144;            // 76800 d
    double* sg   = feat + 76800;           // 256 d
    double* ke   = sg + 256;               // 76800 d
    float*  part = (float*)(ke + 76800);   // 64*76800 f32 = 19.66 MB

    k_wt<<<1024, 256, 0, stream>>>(conv_w, wT);
    k_conv<<<dim3(75, KC), 256, 0, stream>>>(x, wT, part);
    k_reduce<<<300, 256, 0, stream>>>(part, conv_b, g1, b1, m1, v1, feat);
    k_atten<<<16, 256, 0, stream>>>(feat, aw, g2, b2, m2, v2, sg);
    k_knn<<<4800, 320, 0, stream>>>(feat, sg, lw, lb, ke);
    k_up<<<4800, 256, 0, stream>>>(ke, out);
}

// Round 14
// 201.521 us; speedup vs baseline: 2.2918x; 2.0206x over previous
//
#include <hip/hip_runtime.h>
#include <math.h>

#define EPSV 1e-5
#define HW_IN (240 * 320)
#define NPTS 300
#define NPATCH 4800
#define KC 64        // one input channel per chunk
#define EPS_BLEND 2.5e-4
#define W_MAX 0.35

// ---------------- weight transpose to f64: wT[k][oc] = (double)w[oc][k] ----------------
__global__ __launch_bounds__(256) void k_wt(const float* __restrict__ w, double* __restrict__ wT) {
    int t = blockIdx.x * 256 + threadIdx.x;   // t = k*16 + oc
    int k = t >> 4, oc = t & 15;
    wT[t] = (double)w[oc * 16384 + k];
}

// ---------------- conv chunk: part[ic][p][oc], f64 accumulate, f32 out ----------------
// grid (25, 64), block 192 = 3 waves, 4800 waves total (r11's shape). The block stages its
// ic's 32 KB f64 weight slice into LDS once (coalesced double2); the FMA loop then reads
// weights via wave-uniform ds_read broadcast (conflict-free, batched under lgkmcnt) instead
// of the serialized s_load stream that stalled r11-r13. Per-(p,oc) FMA k-order unchanged
// -> feat BIT-IDENTICAL to r11. No barriers after staging; waves run independently.
__global__ __launch_bounds__(192) void k_conv(const float* __restrict__ x, const double* __restrict__ wT,
                                              float* __restrict__ part) {
    __shared__ __align__(16) double wlds[4096];   // 32 KB: [k=0..255][oc=0..15]
    int tid = threadIdx.x;
    int ic = blockIdx.y;                      // 0..63
    {
        const double2* wsrc = (const double2*)(wT + (size_t)ic * 4096);
        double2* wdst = (double2*)wlds;
        for (int j = tid; j < 2048; j += 192) wdst[j] = wsrc[j];
    }
    __syncthreads();

    int p = blockIdx.x * 192 + tid;           // 0..4799
    int b = p / NPTS;
    int r = p - b * NPTS;
    int oh = r / 20;
    int ow = r - oh * 20;
    const float* xp = x + (size_t)b * (64 * HW_IN) + (size_t)ic * HW_IN + (oh * 16) * 320 + ow * 16;
    double acc[16];
#pragma unroll
    for (int o = 0; o < 16; ++o) acc[o] = 0.0;

    float4 cur0, cur1, cur2, cur3, nxt0, nxt1, nxt2, nxt3;
    {
        const float4* rp = (const float4*)xp;
        cur0 = rp[0]; cur1 = rp[1]; cur2 = rp[2]; cur3 = rp[3];
    }
    for (int kh = 0; kh < 16; ++kh) {
        if (kh < 15) {                        // prefetch next row before the FMA block
            const float4* rn = (const float4*)(xp + (kh + 1) * 320);
            nxt0 = rn[0]; nxt1 = rn[1]; nxt2 = rn[2]; nxt3 = rn[3];
        }
        float4 rq[4] = {cur0, cur1, cur2, cur3};
#pragma unroll
        for (int q = 0; q < 4; ++q) {
            float xe[4] = {rq[q].x, rq[q].y, rq[q].z, rq[q].w};
#pragma unroll
            for (int e = 0; e < 4; ++e) {
                double xd = (double)xe[e];
                const double* wq = wlds + (size_t)(kh * 16 + q * 4 + e) * 16;  // wave-uniform LDS broadcast
#pragma unroll
                for (int o = 0; o < 16; ++o) acc[o] += xd * wq[o];
            }
        }
        cur0 = nxt0; cur1 = nxt1; cur2 = nxt2; cur3 = nxt3;
    }
    float4* dst = (float4*)(part + ((size_t)ic * NPATCH + p) * 16);
#pragma unroll
    for (int q = 0; q < 4; ++q)
        dst[q] = make_float4((float)acc[4 * q], (float)acc[4 * q + 1],
                             (float)acc[4 * q + 2], (float)acc[4 * q + 3]);
}

// ---------------- reduce partials (ic order) + bias + BN1 + relu -> feat f64 (B,N,C) ----------------
__global__ __launch_bounds__(256) void k_reduce(const float* __restrict__ part, const float* __restrict__ cb,
                                                const float* __restrict__ g, const float* __restrict__ be,
                                                const float* __restrict__ mu, const float* __restrict__ va,
                                                double* __restrict__ feat) {
    int t = blockIdx.x * 256 + threadIdx.x;   // (p, oc) flat, 76800 total
    double s = 0.0;
#pragma unroll 8
    for (int ic = 0; ic < KC; ++ic) s += (double)part[(size_t)ic * 76800 + t];
    int oc = t & 15;
    double v = s + (double)cb[oc];
    double rs = 1.0 / sqrt((double)va[oc] + EPSV);
    double f = (double)g[oc] * (v - (double)mu[oc]) * rs + (double)be[oc];
    feat[t] = fmax(f, 0.0);
}

// ---------------- attention gate: grid 16 (one per batch) ----------------
__global__ __launch_bounds__(256) void k_atten(const double* __restrict__ feat, const float* __restrict__ aw,
                                               const float* __restrict__ g2, const float* __restrict__ be2,
                                               const float* __restrict__ mu2, const float* __restrict__ va2,
                                               double* __restrict__ sg) {
    __shared__ double partial[256];
    __shared__ double am[16];
    int b = blockIdx.x;
    int t = threadIdx.x;
    int c = t & 15, seg = t >> 4;
    double s = 0.0;
    for (int n = seg; n < NPTS; n += 16) s += feat[(size_t)b * 4800 + n * 16 + c];
    partial[t] = s;
    __syncthreads();
    if (t < 16) {
        double s2 = 0.0;
        for (int sgm = 0; sgm < 16; ++sgm) s2 += partial[sgm * 16 + t];
        am[t] = s2 / 300.0;
    }
    __syncthreads();
    if (t < 16) {
        double a = 0.0;
        for (int j = 0; j < 16; ++j) a += am[j] * (double)aw[t * 16 + j];
        double rs = 1.0 / sqrt((double)va2[t] + EPSV);
        double v = (double)g2[t] * (a - (double)mu2[t]) * rs + (double)be2[t];
        sg[b * 16 + t] = 1.0 / (1.0 + exp(-v));
    }
}

// ---------------- per-(b,i): f64 dist -> rank count (b128 key reads) -> hedged mean -> linear ----------------
__global__ __launch_bounds__(320) void k_knn(const double* __restrict__ feat, const double* __restrict__ sg,
                                             const float* __restrict__ lw, const float* __restrict__ lb,
                                             double* __restrict__ ke) {
    __shared__ __align__(16) double dsh[NPTS];
    __shared__ short rankidx[NPTS];
    __shared__ double qv[16];
    __shared__ double sgs[16];
    __shared__ double mvec[16];
    const int tid = threadIdx.x;
    const int blk = blockIdx.x;
    const int b = blk / NPTS;
    const int i = blk - b * NPTS;
    const double* fb = feat + (size_t)b * 4800;

    if (tid < NPTS) rankidx[tid] = (short)tid;   // guard for measure-zero exact ties
    if (tid < 16) {
        double sv = sg[b * 16 + tid];
        sgs[tid] = sv;
        qv[tid] = fb[i * 16 + tid] * sv;
    }
    __syncthreads();
    if (tid < NPTS) {
        const double* fr = fb + (size_t)tid * 16;
        double s2 = 0.0;
#pragma unroll
        for (int c = 0; c < 16; ++c) {
            double d = qv[c] - fr[c] * sgs[c];
            s2 += d * d;
        }
        dsh[tid] = sqrt(s2);
    }
    __syncthreads();
    if (tid < NPTS) {
        double dj = dsh[tid];
        int rank = 0;
        const double2* d2 = (const double2*)dsh;
#pragma unroll 10
        for (int t = 0; t < 150; ++t) {
            double2 kk = d2[t];                  // broadcast ds_read_b128: 2 keys/op
            rank += (kk.x > dj);
            rank += (kk.y > dj);                 // exact ties measure-zero in f64
        }
        rankidx[rank] = (short)tid;
    }
    __syncthreads();
    if (tid < 16) {   // tid = channel c; hedged mean over the 16 selected ranks
        const int targ[16] = {9, 28, 46, 65, 84, 103, 121, 140, 159, 178,
                              196, 215, 234, 253, 271, 290};
        double acc = 0.0;
        double sc = sgs[tid];
        for (int s = 0; s < 16; ++s) {
            int r = targ[s];
            int a  = rankidx[r];
            int u  = rankidx[r - 1];
            int dn = rankidx[r + 1];
            double gu = dsh[u] - dsh[a];
            double gd = dsh[a] - dsh[dn];
            double wu = W_MAX * fmax(0.0, 1.0 - gu / EPS_BLEND);
            double wd = W_MAX * fmax(0.0, 1.0 - gd / EPS_BLEND);
            double wa = 1.0 - wu - wd;
            acc += wa * (fb[a * 16 + tid] * sc) + wu * (fb[u * 16 + tid] * sc)
                 + wd * (fb[dn * 16 + tid] * sc);
        }
        mvec[tid] = acc * (1.0 / 16.0) - qv[tid];
    }
    __syncthreads();
    if (tid < 16) {   // tid = out channel
        double o = (double)lb[tid];
        for (int c = 0; c < 16; ++c) o += mvec[c] * (double)lw[tid * 16 + c];
        ke[((size_t)b * 16 + tid) * NPTS + i] = o;
    }
}

// ---------------- fused double-bilinear 2x->4x + positional encoding ----------------
__device__ inline void coords2x(int o, int n, int& i0, int& i1, double& w) {
    double s = ((double)o + 0.5) * 0.5 - 0.5;
    s = fmin(fmax(s, 0.0), (double)(n - 1));
    i0 = (int)floor(s);
    i1 = min(i0 + 1, n - 1);
    w = s - (double)i0;
}

__device__ inline double midval(const double* __restrict__ kp, int y, int x) {
    int y0, y1, x0, x1; double wy, wx;
    coords2x(y, 15, y0, y1, wy);
    coords2x(x, 20, x0, x1, wx);
    double v00 = kp[y0 * 20 + x0], v01 = kp[y0 * 20 + x1];
    double v10 = kp[y1 * 20 + x0], v11 = kp[y1 * 20 + x1];
    return (v00 * (1.0 - wy) + v10 * wy) * (1.0 - wx) + (v01 * (1.0 - wy) + v11 * wy) * wx;
}

__global__ __launch_bounds__(256) void k_up(const double* __restrict__ ke, float* __restrict__ out) {
    int idx = blockIdx.x * 256 + threadIdx.x;   // (b, c, 60, 80) = 1,228,800 threads
    int bc = idx / 4800;
    int r2 = idx - bc * 4800;
    int Y = r2 / 80, X = r2 - Y * 80;
    int c = bc & 15;
    int y0, y1, x0, x1; double wy, wx;
    coords2x(Y, 30, y0, y1, wy);
    coords2x(X, 40, x0, x1, wx);
    const double* kp = ke + (size_t)bc * 300;
    double v00 = midval(kp, y0, x0), v01 = midval(kp, y0, x1);
    double v10 = midval(kp, y1, x0), v11 = midval(kp, y1, x1);
    double u = (v00 * (1.0 - wy) + v10 * wy) * (1.0 - wx) + (v01 * (1.0 - wy) + v11 * wy) * wx;
    const float scf[4] = {1.0f, 0.1f, 0.01f, 0.001f};   // exp(-2m*ln(1e4)/8) = 10^-m
    int m = c >> 2, rr = c & 3;
    float pos = (rr < 2) ? (float)(X + 1) : (float)(Y + 1);
    float ang = pos * scf[m];
    float pe = (rr & 1) ? cosf(ang) : sinf(ang);    // f32 trig: smooth path, error ~1e-7
    out[idx] = (float)(u + (u + (double)pe));       // knn_edge + (knn_edge + pe)
}

extern "C" void kernel_launch(void* const* d_in, const int* in_sizes, int n_in,
                              void* d_out, int out_size, void* d_ws, size_t ws_size,
                              hipStream_t stream) {
    const float* x      = (const float*)d_in[0];
    const float* conv_w = (const float*)d_in[1];
    const float* conv_b = (const float*)d_in[2];
    const float* g1     = (const float*)d_in[3];
    const float* b1     = (const float*)d_in[4];
    const float* m1     = (const float*)d_in[5];
    const float* v1     = (const float*)d_in[6];
    const float* aw     = (const float*)d_in[7];
    const float* g2     = (const float*)d_in[8];
    const float* b2     = (const float*)d_in[9];
    const float* m2     = (const float*)d_in[10];
    const float* v2     = (const float*)d_in[11];
    const float* lw     = (const float*)d_in[12];
    const float* lb     = (const float*)d_in[13];
    float* out = (float*)d_out;

    double* ws   = (double*)d_ws;
    double* wT   = ws;                     // 262144 d (2.10 MB)
    double* feat = wT + 262144;            // 76800 d
    double* sg   = feat + 76800;           // 256 d
    double* ke   = sg + 256;               // 76800 d
    float*  part = (float*)(ke + 76800);   // 64*76800 f32 = 19.66 MB

    k_wt<<<1024, 256, 0, stream>>>(conv_w, wT);
    k_conv<<<dim3(25, KC), 192, 0, stream>>>(x, wT, part);
    k_reduce<<<300, 256, 0, stream>>>(part, conv_b, g1, b1, m1, v1, feat);
    k_atten<<<16, 256, 0, stream>>>(feat, aw, g2, b2, m2, v2, sg);
    k_knn<<<4800, 320, 0, stream>>>(feat, sg, lw, lb, ke);
    k_up<<<4800, 256, 0, stream>>>(ke, out);
}

// Round 15
// 194.437 us; speedup vs baseline: 2.3753x; 1.0364x over previous
//
#include <hip/hip_runtime.h>
#include <math.h>

#define EPSV 1e-5
#define HW_IN (240 * 320)
#define NPTS 300
#define NPATCH 4800
#define KC 64        // one input channel per chunk
#define EPS_BLEND 2.5e-4
#define W_MAX 0.35

// ---------------- weight transpose to f64: wT[k][oc] = (double)w[oc][k] ----------------
__global__ __launch_bounds__(256) void k_wt(const float* __restrict__ w, double* __restrict__ wT) {
    int t = blockIdx.x * 256 + threadIdx.x;   // t = k*16 + oc
    int k = t >> 4, oc = t & 15;
    wT[t] = (double)w[oc * 16384 + k];
}

// ---------------- conv chunk: part[ic][p][oc], f64 accumulate, f32 out ----------------
// grid (25, 64), block 64 (1 wave). Register tiling: each lane owns 3 patches
// {p, p+1600, p+3200}, so every weight value loaded feeds 3 FMAs (48 FMAs = 192 cy per
// 16-double group vs ~120 cy load latency — covered). x loaded once per patch, coalesced.
// Per-(p,oc) FMA k-order identical to r11 -> feat BIT-IDENTICAL.
__global__ __launch_bounds__(64) void k_conv(const float* __restrict__ x, const double* __restrict__ wT,
                                             float* __restrict__ part) {
    int lane = threadIdx.x;
    int base = blockIdx.x * 64 + lane;        // 0..1599
    int ic = blockIdx.y;                      // 0..63
    const float* xp0;
    const float* xp1;
    const float* xp2;
    {
        int p = base;
        int b = p / NPTS, r = p - b * NPTS, oh = r / 20, ow = r - oh * 20;
        xp0 = x + (size_t)b * (64 * HW_IN) + (size_t)ic * HW_IN + (oh * 16) * 320 + ow * 16;
        p = base + 1600;
        b = p / NPTS; r = p - b * NPTS; oh = r / 20; ow = r - oh * 20;
        xp1 = x + (size_t)b * (64 * HW_IN) + (size_t)ic * HW_IN + (oh * 16) * 320 + ow * 16;
        p = base + 3200;
        b = p / NPTS; r = p - b * NPTS; oh = r / 20; ow = r - oh * 20;
        xp2 = x + (size_t)b * (64 * HW_IN) + (size_t)ic * HW_IN + (oh * 16) * 320 + ow * 16;
    }
    const double* wk = wT + (size_t)(ic * 256) * 16;
    double acc0[16], acc1[16], acc2[16];
#pragma unroll
    for (int o = 0; o < 16; ++o) { acc0[o] = 0.0; acc1[o] = 0.0; acc2[o] = 0.0; }

    for (int kh = 0; kh < 16; ++kh) {
        const float4* r0 = (const float4*)(xp0 + kh * 320);
        const float4* r1 = (const float4*)(xp1 + kh * 320);
        const float4* r2 = (const float4*)(xp2 + kh * 320);
        float4 a0[4], a1[4], a2[4];           // 12 independent loads issued up front
#pragma unroll
        for (int q = 0; q < 4; ++q) { a0[q] = r0[q]; a1[q] = r1[q]; a2[q] = r2[q]; }
#pragma unroll
        for (int q = 0; q < 4; ++q) {
            float x0e[4] = {a0[q].x, a0[q].y, a0[q].z, a0[q].w};
            float x1e[4] = {a1[q].x, a1[q].y, a1[q].z, a1[q].w};
            float x2e[4] = {a2[q].x, a2[q].y, a2[q].z, a2[q].w};
#pragma unroll
            for (int e = 0; e < 4; ++e) {
                double xd0 = (double)x0e[e];
                double xd1 = (double)x1e[e];
                double xd2 = (double)x2e[e];
                const double* wq = wk + (size_t)(kh * 16 + q * 4 + e) * 16;  // wave-uniform
#pragma unroll
                for (int o = 0; o < 16; ++o) {
                    double w = wq[o];          // one load, three FMAs
                    acc0[o] += xd0 * w;
                    acc1[o] += xd1 * w;
                    acc2[o] += xd2 * w;
                }
            }
        }
    }
    {
        float4* d0 = (float4*)(part + ((size_t)ic * NPATCH + base) * 16);
        float4* d1 = (float4*)(part + ((size_t)ic * NPATCH + base + 1600) * 16);
        float4* d2 = (float4*)(part + ((size_t)ic * NPATCH + base + 3200) * 16);
#pragma unroll
        for (int q = 0; q < 4; ++q) {
            d0[q] = make_float4((float)acc0[4 * q], (float)acc0[4 * q + 1],
                                (float)acc0[4 * q + 2], (float)acc0[4 * q + 3]);
            d1[q] = make_float4((float)acc1[4 * q], (float)acc1[4 * q + 1],
                                (float)acc1[4 * q + 2], (float)acc1[4 * q + 3]);
            d2[q] = make_float4((float)acc2[4 * q], (float)acc2[4 * q + 1],
                                (float)acc2[4 * q + 2], (float)acc2[4 * q + 3]);
        }
    }
}

// ---------------- reduce partials (ic order) + bias + BN1 + relu -> feat f64 (B,N,C) ----------------
__global__ __launch_bounds__(256) void k_reduce(const float* __restrict__ part, const float* __restrict__ cb,
                                                const float* __restrict__ g, const float* __restrict__ be,
                                                const float* __restrict__ mu, const float* __restrict__ va,
                                                double* __restrict__ feat) {
    int t = blockIdx.x * 256 + threadIdx.x;   // (p, oc) flat, 76800 total
    double s = 0.0;
#pragma unroll 8
    for (int ic = 0; ic < KC; ++ic) s += (double)part[(size_t)ic * 76800 + t];
    int oc = t & 15;
    double v = s + (double)cb[oc];
    double rs = 1.0 / sqrt((double)va[oc] + EPSV);
    double f = (double)g[oc] * (v - (double)mu[oc]) * rs + (double)be[oc];
    feat[t] = fmax(f, 0.0);
}

// ---------------- attention gate: grid 16 (one per batch) ----------------
__global__ __launch_bounds__(256) void k_atten(const double* __restrict__ feat, const float* __restrict__ aw,
                                               const float* __restrict__ g2, const float* __restrict__ be2,
                                               const float* __restrict__ mu2, const float* __restrict__ va2,
                                               double* __restrict__ sg) {
    __shared__ double partial[256];
    __shared__ double am[16];
    int b = blockIdx.x;
    int t = threadIdx.x;
    int c = t & 15, seg = t >> 4;
    double s = 0.0;
    for (int n = seg; n < NPTS; n += 16) s += feat[(size_t)b * 4800 + n * 16 + c];
    partial[t] = s;
    __syncthreads();
    if (t < 16) {
        double s2 = 0.0;
        for (int sgm = 0; sgm < 16; ++sgm) s2 += partial[sgm * 16 + t];
        am[t] = s2 / 300.0;
    }
    __syncthreads();
    if (t < 16) {
        double a = 0.0;
        for (int j = 0; j < 16; ++j) a += am[j] * (double)aw[t * 16 + j];
        double rs = 1.0 / sqrt((double)va2[t] + EPSV);
        double v = (double)g2[t] * (a - (double)mu2[t]) * rs + (double)be2[t];
        sg[b * 16 + t] = 1.0 / (1.0 + exp(-v));
    }
}

// ---------------- per-(b,i): f64 dist -> rank count (b128 key reads) -> hedged mean -> linear ----------------
__global__ __launch_bounds__(320) void k_knn(const double* __restrict__ feat, const double* __restrict__ sg,
                                             const float* __restrict__ lw, const float* __restrict__ lb,
                                             double* __restrict__ ke) {
    __shared__ __align__(16) double dsh[NPTS];
    __shared__ short rankidx[NPTS];
    __shared__ double qv[16];
    __shared__ double sgs[16];
    __shared__ double mvec[16];
    const int tid = threadIdx.x;
    const int blk = blockIdx.x;
    const int b = blk / NPTS;
    const int i = blk - b * NPTS;
    const double* fb = feat + (size_t)b * 4800;

    if (tid < NPTS) rankidx[tid] = (short)tid;   // guard for measure-zero exact ties
    if (tid < 16) {
        double sv = sg[b * 16 + tid];
        sgs[tid] = sv;
        qv[tid] = fb[i * 16 + tid] * sv;
    }
    __syncthreads();
    if (tid < NPTS) {
        const double* fr = fb + (size_t)tid * 16;
        double s2 = 0.0;
#pragma unroll
        for (int c = 0; c < 16; ++c) {
            double d = qv[c] - fr[c] * sgs[c];
            s2 += d * d;
        }
        dsh[tid] = sqrt(s2);
    }
    __syncthreads();
    if (tid < NPTS) {
        double dj = dsh[tid];
        int rank = 0;
        const double2* d2 = (const double2*)dsh;
#pragma unroll 10
        for (int t = 0; t < 150; ++t) {
            double2 kk = d2[t];                  // broadcast ds_read_b128: 2 keys/op
            rank += (kk.x > dj);
            rank += (kk.y > dj);                 // exact ties measure-zero in f64
        }
        rankidx[rank] = (short)tid;
    }
    __syncthreads();
    if (tid < 16) {   // tid = channel c; hedged mean over the 16 selected ranks
        const int targ[16] = {9, 28, 46, 65, 84, 103, 121, 140, 159, 178,
                              196, 215, 234, 253, 271, 290};
        double acc = 0.0;
        double sc = sgs[tid];
        for (int s = 0; s < 16; ++s) {
            int r = targ[s];
            int a  = rankidx[r];
            int u  = rankidx[r - 1];
            int dn = rankidx[r + 1];
            double gu = dsh[u] - dsh[a];
            double gd = dsh[a] - dsh[dn];
            double wu = W_MAX * fmax(0.0, 1.0 - gu / EPS_BLEND);
            double wd = W_MAX * fmax(0.0, 1.0 - gd / EPS_BLEND);
            double wa = 1.0 - wu - wd;
            acc += wa * (fb[a * 16 + tid] * sc) + wu * (fb[u * 16 + tid] * sc)
                 + wd * (fb[dn * 16 + tid] * sc);
        }
        mvec[tid] = acc * (1.0 / 16.0) - qv[tid];
    }
    __syncthreads();
    if (tid < 16) {   // tid = out channel
        double o = (double)lb[tid];
        for (int c = 0; c < 16; ++c) o += mvec[c] * (double)lw[tid * 16 + c];
        ke[((size_t)b * 16 + tid) * NPTS + i] = o;
    }
}

// ---------------- fused double-bilinear 2x->4x + positional encoding ----------------
__device__ inline void coords2x(int o, int n, int& i0, int& i1, double& w) {
    double s = ((double)o + 0.5) * 0.5 - 0.5;
    s = fmin(fmax(s, 0.0), (double)(n - 1));
    i0 = (int)floor(s);
    i1 = min(i0 + 1, n - 1);
    w = s - (double)i0;
}

__device__ inline double midval(const double* __restrict__ kp, int y, int x) {
    int y0, y1, x0, x1; double wy, wx;
    coords2x(y, 15, y0, y1, wy);
    coords2x(x, 20, x0, x1, wx);
    double v00 = kp[y0 * 20 + x0], v01 = kp[y0 * 20 + x1];
    double v10 = kp[y1 * 20 + x0], v11 = kp[y1 * 20 + x1];
    return (v00 * (1.0 - wy) + v10 * wy) * (1.0 - wx) + (v01 * (1.0 - wy) + v11 * wy) * wx;
}

__global__ __launch_bounds__(256) void k_up(const double* __restrict__ ke, float* __restrict__ out) {
    int idx = blockIdx.x * 256 + threadIdx.x;   // (b, c, 60, 80) = 1,228,800 threads
    int bc = idx / 4800;
    int r2 = idx - bc * 4800;
    int Y = r2 / 80, X = r2 - Y * 80;
    int c = bc & 15;
    int y0, y1, x0, x1; double wy, wx;
    coords2x(Y, 30, y0, y1, wy);
    coords2x(X, 40, x0, x1, wx);
    const double* kp = ke + (size_t)bc * 300;
    double v00 = midval(kp, y0, x0), v01 = midval(kp, y0, x1);
    double v10 = midval(kp, y1, x0), v11 = midval(kp, y1, x1);
    double u = (v00 * (1.0 - wy) + v10 * wy) * (1.0 - wx) + (v01 * (1.0 - wy) + v11 * wy) * wx;
    const float scf[4] = {1.0f, 0.1f, 0.01f, 0.001f};   // exp(-2m*ln(1e4)/8) = 10^-m
    int m = c >> 2, rr = c & 3;
    float pos = (rr < 2) ? (float)(X + 1) : (float)(Y + 1);
    float ang = pos * scf[m];
    float pe = (rr & 1) ? cosf(ang) : sinf(ang);    // f32 trig: smooth path, error ~1e-7
    out[idx] = (float)(u + (u + (double)pe));       // knn_edge + (knn_edge + pe)
}

extern "C" void kernel_launch(void* const* d_in, const int* in_sizes, int n_in,
                              void* d_out, int out_size, void* d_ws, size_t ws_size,
                              hipStream_t stream) {
    const float* x      = (const float*)d_in[0];
    const float* conv_w = (const float*)d_in[1];
    const float* conv_b = (const float*)d_in[2];
    const float* g1     = (const float*)d_in[3];
    const float* b1     = (const float*)d_in[4];
    const float* m1     = (const float*)d_in[5];
    const float* v1     = (const float*)d_in[6];
    const float* aw     = (const float*)d_in[7];
    const float* g2     = (const float*)d_in[8];
    const float* b2     = (const float*)d_in[9];
    const float* m2     = (const float*)d_in[10];
    const float* v2     = (const float*)d_in[11];
    const float* lw     = (const float*)d_in[12];
    const float* lb     = (const float*)d_in[13];
    float* out = (float*)d_out;

    double* ws   = (double*)d_ws;
    double* wT   = ws;                     // 262144 d (2.10 MB)
    double* feat = wT + 262144;            // 76800 d
    double* sg   = feat + 76800;           // 256 d
    double* ke   = sg + 256;               // 76800 d
    float*  part = (float*)(ke + 76800);   // 64*76800 f32 = 19.66 MB

    k_wt<<<1024, 256, 0, stream>>>(conv_w, wT);
    k_conv<<<dim3(25, KC), 64, 0, stream>>>(x, wT, part);
    k_reduce<<<300, 256, 0, stream>>>(part, conv_b, g1, b1, m1, v1, feat);
    k_atten<<<16, 256, 0, stream>>>(feat, aw, g2, b2, m2, v2, sg);
    k_knn<<<4800, 320, 0, stream>>>(feat, sg, lw, lb, ke);
    k_up<<<4800, 256, 0, stream>>>(ke, out);
}

// Round 16
// 185.638 us; speedup vs baseline: 2.4879x; 1.0474x over previous
//
#include <hip/hip_runtime.h>
#include <math.h>

#define EPSV 1e-5
#define HW_IN (240 * 320)
#define NPTS 300
#define NPATCH 4800
#define KC 64        // one input channel per chunk
#define EPS_BLEND 2.5e-4
#define W_MAX 0.35

// ---------------- weight transpose to f64: wT[k][oc] = (double)w[oc][k] ----------------
__global__ __launch_bounds__(256) void k_wt(const float* __restrict__ w, double* __restrict__ wT) {
    int t = blockIdx.x * 256 + threadIdx.x;   // t = k*16 + oc
    int k = t >> 4, oc = t & 15;
    wT[t] = (double)w[oc * 16384 + k];
}

#define XCOMP(v, e) ((e) == 0 ? (v).x : (e) == 1 ? (v).y : (e) == 2 ? (v).z : (v).w)

#define LOADGRP(WB, gi) { \
    const double* wq_ = wk + (size_t)(gi) * 16; \
    _Pragma("unroll") \
    for (int o = 0; o < 16; ++o) WB[o] = wq_[o]; }

#define FMAGRP(WB, g) { \
    const int q_ = (g) >> 2, e_ = (g) & 3; \
    double xd0 = (double)XCOMP(a0[q_], e_); \
    double xd1 = (double)XCOMP(a1[q_], e_); \
    double xd2 = (double)XCOMP(a2[q_], e_); \
    _Pragma("unroll") \
    for (int o = 0; o < 16; ++o) { \
        double w_ = WB[o]; \
        acc0[o] += xd0 * w_; acc1[o] += xd1 * w_; acc2[o] += xd2 * w_; } }

// ---------------- conv chunk: part[ic][p][oc], f64 accumulate, f32 out ----------------
// grid (25, 64), block 64 (1 wave), 3 patches/lane (r15). NEW: weight-group software
// pipeline — statically-named double buffers wb0/wb1, load group g+1 issued BEFORE the
// FMAs of group g, so each 16-weight L2 wait hides under 192 cy of the previous group's
// FMAs (the serial per-group wait that bounded r11-r15). Load order changes only;
// per-(p,oc) FMA order unchanged -> feat BIT-IDENTICAL.
__global__ __launch_bounds__(64) void k_conv(const float* __restrict__ x, const double* __restrict__ wT,
                                             float* __restrict__ part) {
    int lane = threadIdx.x;
    int base = blockIdx.x * 64 + lane;        // 0..1599
    int ic = blockIdx.y;                      // 0..63
    const float* xp0;
    const float* xp1;
    const float* xp2;
    {
        int p = base;
        int b = p / NPTS, r = p - b * NPTS, oh = r / 20, ow = r - oh * 20;
        xp0 = x + (size_t)b * (64 * HW_IN) + (size_t)ic * HW_IN + (oh * 16) * 320 + ow * 16;
        p = base + 1600;
        b = p / NPTS; r = p - b * NPTS; oh = r / 20; ow = r - oh * 20;
        xp1 = x + (size_t)b * (64 * HW_IN) + (size_t)ic * HW_IN + (oh * 16) * 320 + ow * 16;
        p = base + 3200;
        b = p / NPTS; r = p - b * NPTS; oh = r / 20; ow = r - oh * 20;
        xp2 = x + (size_t)b * (64 * HW_IN) + (size_t)ic * HW_IN + (oh * 16) * 320 + ow * 16;
    }
    const double* wk = wT + (size_t)(ic * 256) * 16;
    double acc0[16], acc1[16], acc2[16];
#pragma unroll
    for (int o = 0; o < 16; ++o) { acc0[o] = 0.0; acc1[o] = 0.0; acc2[o] = 0.0; }

    double wb0[16], wb1[16];
    LOADGRP(wb0, 0);                          // prime the pipeline with group 0
    for (int kh = 0; kh < 16; ++kh) {
        const float4* r0 = (const float4*)(xp0 + kh * 320);
        const float4* r1 = (const float4*)(xp1 + kh * 320);
        const float4* r2 = (const float4*)(xp2 + kh * 320);
        float4 a0[4], a1[4], a2[4];           // 12 independent x loads issued up front
#pragma unroll
        for (int q = 0; q < 4; ++q) { a0[q] = r0[q]; a1[q] = r1[q]; a2[q] = r2[q]; }
#pragma unroll
        for (int h = 0; h < 8; ++h) {
            const int g0 = 2 * h, g1 = 2 * h + 1;
            int gi1 = kh * 16 + g1;           // group index of g1 (= group after g0)
            int gi2 = gi1 + 1; if (gi2 > 255) gi2 = 255;   // clamp: harmless reload at end
            LOADGRP(wb1, gi1);                // issue next group's loads...
            FMAGRP(wb0, g0);                  // ...then crunch the current group
            LOADGRP(wb0, gi2);
            FMAGRP(wb1, g1);
        }
    }
    {
        float4* d0 = (float4*)(part + ((size_t)ic * NPATCH + base) * 16);
        float4* d1 = (float4*)(part + ((size_t)ic * NPATCH + base + 1600) * 16);
        float4* d2 = (float4*)(part + ((size_t)ic * NPATCH + base + 3200) * 16);
#pragma unroll
        for (int q = 0; q < 4; ++q) {
            d0[q] = make_float4((float)acc0[4 * q], (float)acc0[4 * q + 1],
                                (float)acc0[4 * q + 2], (float)acc0[4 * q + 3]);
            d1[q] = make_float4((float)acc1[4 * q], (float)acc1[4 * q + 1],
                                (float)acc1[4 * q + 2], (float)acc1[4 * q + 3]);
            d2[q] = make_float4((float)acc2[4 * q], (float)acc2[4 * q + 1],
                                (float)acc2[4 * q + 2], (float)acc2[4 * q + 3]);
        }
    }
}

// ---------------- reduce partials (ic order) + bias + BN1 + relu -> feat f64 (B,N,C) ----------------
__global__ __launch_bounds__(256) void k_reduce(const float* __restrict__ part, const float* __restrict__ cb,
                                                const float* __restrict__ g, const float* __restrict__ be,
                                                const float* __restrict__ mu, const float* __restrict__ va,
                                                double* __restrict__ feat) {
    int t = blockIdx.x * 256 + threadIdx.x;   // (p, oc) flat, 76800 total
    double s = 0.0;
#pragma unroll 8
    for (int ic = 0; ic < KC; ++ic) s += (double)part[(size_t)ic * 76800 + t];
    int oc = t & 15;
    double v = s + (double)cb[oc];
    double rs = 1.0 / sqrt((double)va[oc] + EPSV);
    double f = (double)g[oc] * (v - (double)mu[oc]) * rs + (double)be[oc];
    feat[t] = fmax(f, 0.0);
}

// ---------------- attention gate: grid 16 (one per batch) ----------------
__global__ __launch_bounds__(256) void k_atten(const double* __restrict__ feat, const float* __restrict__ aw,
                                               const float* __restrict__ g2, const float* __restrict__ be2,
                                               const float* __restrict__ mu2, const float* __restrict__ va2,
                                               double* __restrict__ sg) {
    __shared__ double partial[256];
    __shared__ double am[16];
    int b = blockIdx.x;
    int t = threadIdx.x;
    int c = t & 15, seg = t >> 4;
    double s = 0.0;
    for (int n = seg; n < NPTS; n += 16) s += feat[(size_t)b * 4800 + n * 16 + c];
    partial[t] = s;
    __syncthreads();
    if (t < 16) {
        double s2 = 0.0;
        for (int sgm = 0; sgm < 16; ++sgm) s2 += partial[sgm * 16 + t];
        am[t] = s2 / 300.0;
    }
    __syncthreads();
    if (t < 16) {
        double a = 0.0;
        for (int j = 0; j < 16; ++j) a += am[j] * (double)aw[t * 16 + j];
        double rs = 1.0 / sqrt((double)va2[t] + EPSV);
        double v = (double)g2[t] * (a - (double)mu2[t]) * rs + (double)be2[t];
        sg[b * 16 + t] = 1.0 / (1.0 + exp(-v));
    }
}

// ---------------- per-(b,i): f64 dist -> rank count (b128 key reads) -> hedged mean -> linear ----------------
__global__ __launch_bounds__(320) void k_knn(const double* __restrict__ feat, const double* __restrict__ sg,
                                             const float* __restrict__ lw, const float* __restrict__ lb,
                                             double* __restrict__ ke) {
    __shared__ __align__(16) double dsh[NPTS];
    __shared__ short rankidx[NPTS];
    __shared__ double qv[16];
    __shared__ double sgs[16];
    __shared__ double mvec[16];
    const int tid = threadIdx.x;
    const int blk = blockIdx.x;
    const int b = blk / NPTS;
    const int i = blk - b * NPTS;
    const double* fb = feat + (size_t)b * 4800;

    if (tid < NPTS) rankidx[tid] = (short)tid;   // guard for measure-zero exact ties
    if (tid < 16) {
        double sv = sg[b * 16 + tid];
        sgs[tid] = sv;
        qv[tid] = fb[i * 16 + tid] * sv;
    }
    __syncthreads();
    if (tid < NPTS) {
        const double* fr = fb + (size_t)tid * 16;
        double s2 = 0.0;
#pragma unroll
        for (int c = 0; c < 16; ++c) {
            double d = qv[c] - fr[c] * sgs[c];
            s2 += d * d;
        }
        dsh[tid] = sqrt(s2);
    }
    __syncthreads();
    if (tid < NPTS) {
        double dj = dsh[tid];
        int rank = 0;
        const double2* d2 = (const double2*)dsh;
#pragma unroll 10
        for (int t = 0; t < 150; ++t) {
            double2 kk = d2[t];                  // broadcast ds_read_b128: 2 keys/op
            rank += (kk.x > dj);
            rank += (kk.y > dj);                 // exact ties measure-zero in f64
        }
        rankidx[rank] = (short)tid;
    }
    __syncthreads();
    if (tid < 16) {   // tid = channel c; hedged mean over the 16 selected ranks
        const int targ[16] = {9, 28, 46, 65, 84, 103, 121, 140, 159, 178,
                              196, 215, 234, 253, 271, 290};
        double acc = 0.0;
        double sc = sgs[tid];
        for (int s = 0; s < 16; ++s) {
            int r = targ[s];
            int a  = rankidx[r];
            int u  = rankidx[r - 1];
            int dn = rankidx[r + 1];
            double gu = dsh[u] - dsh[a];
            double gd = dsh[a] - dsh[dn];
            double wu = W_MAX * fmax(0.0, 1.0 - gu / EPS_BLEND);
            double wd = W_MAX * fmax(0.0, 1.0 - gd / EPS_BLEND);
            double wa = 1.0 - wu - wd;
            acc += wa * (fb[a * 16 + tid] * sc) + wu * (fb[u * 16 + tid] * sc)
                 + wd * (fb[dn * 16 + tid] * sc);
        }
        mvec[tid] = acc * (1.0 / 16.0) - qv[tid];
    }
    __syncthreads();
    if (tid < 16) {   // tid = out channel
        double o = (double)lb[tid];
        for (int c = 0; c < 16; ++c) o += mvec[c] * (double)lw[tid * 16 + c];
        ke[((size_t)b * 16 + tid) * NPTS + i] = o;
    }
}

// ---------------- fused double-bilinear 2x->4x + positional encoding ----------------
__device__ inline void coords2x(int o, int n, int& i0, int& i1, double& w) {
    double s = ((double)o + 0.5) * 0.5 - 0.5;
    s = fmin(fmax(s, 0.0), (double)(n - 1));
    i0 = (int)floor(s);
    i1 = min(i0 + 1, n - 1);
    w = s - (double)i0;
}

__device__ inline double midval(const double* __restrict__ kp, int y, int x) {
    int y0, y1, x0, x1; double wy, wx;
    coords2x(y, 15, y0, y1, wy);
    coords2x(x, 20, x0, x1, wx);
    double v00 = kp[y0 * 20 + x0], v01 = kp[y0 * 20 + x1];
    double v10 = kp[y1 * 20 + x0], v11 = kp[y1 * 20 + x1];
    return (v00 * (1.0 - wy) + v10 * wy) * (1.0 - wx) + (v01 * (1.0 - wy) + v11 * wy) * wx;
}

__global__ __launch_bounds__(256) void k_up(const double* __restrict__ ke, float* __restrict__ out) {
    int idx = blockIdx.x * 256 + threadIdx.x;   // (b, c, 60, 80) = 1,228,800 threads
    int bc = idx / 4800;
    int r2 = idx - bc * 4800;
    int Y = r2 / 80, X = r2 - Y * 80;
    int c = bc & 15;
    int y0, y1, x0, x1; double wy, wx;
    coords2x(Y, 30, y0, y1, wy);
    coords2x(X, 40, x0, x1, wx);
    const double* kp = ke + (size_t)bc * 300;
    double v00 = midval(kp, y0, x0), v01 = midval(kp, y0, x1);
    double v10 = midval(kp, y1, x0), v11 = midval(kp, y1, x1);
    double u = (v00 * (1.0 - wy) + v10 * wy) * (1.0 - wx) + (v01 * (1.0 - wy) + v11 * wy) * wx;
    const float scf[4] = {1.0f, 0.1f, 0.01f, 0.001f};   // exp(-2m*ln(1e4)/8) = 10^-m
    int m = c >> 2, rr = c & 3;
    float pos = (rr < 2) ? (float)(X + 1) : (float)(Y + 1);
    float ang = pos * scf[m];
    float pe = (rr & 1) ? cosf(ang) : sinf(ang);    // f32 trig: smooth path, error ~1e-7
    out[idx] = (float)(u + (u + (double)pe));       // knn_edge + (knn_edge + pe)
}

extern "C" void kernel_launch(void* const* d_in, const int* in_sizes, int n_in,
                              void* d_out, int out_size, void* d_ws, size_t ws_size,
                              hipStream_t stream) {
    const float* x      = (const float*)d_in[0];
    const float* conv_w = (const float*)d_in[1];
    const float* conv_b = (const float*)d_in[2];
    const float* g1     = (const float*)d_in[3];
    const float* b1     = (const float*)d_in[4];
    const float* m1     = (const float*)d_in[5];
    const float* v1     = (const float*)d_in[6];
    const float* aw     = (const float*)d_in[7];
    const float* g2     = (const float*)d_in[8];
    const float* b2     = (const float*)d_in[9];
    const float* m2     = (const float*)d_in[10];
    const float* v2     = (const float*)d_in[11];
    const float* lw     = (const float*)d_in[12];
    const float* lb     = (const float*)d_in[13];
    float* out = (float*)d_out;

    double* ws   = (double*)d_ws;
    double* wT   = ws;                     // 262144 d (2.10 MB)
    double* feat = wT + 262144;            // 76800 d
    double* sg   = feat + 76800;           // 256 d
    double* ke   = sg + 256;               // 76800 d
    float*  part = (float*)(ke + 76800);   // 64*76800 f32 = 19.66 MB

    k_wt<<<1024, 256, 0, stream>>>(conv_w, wT);
    k_conv<<<dim3(25, KC), 64, 0, stream>>>(x, wT, part);
    k_reduce<<<300, 256, 0, stream>>>(part, conv_b, g1, b1, m1, v1, feat);
    k_atten<<<16, 256, 0, stream>>>(feat, aw, g2, b2, m2, v2, sg);
    k_knn<<<4800, 320, 0, stream>>>(feat, sg, lw, lb, ke);
    k_up<<<4800, 256, 0, stream>>>(ke, out);
}